// Round 8
// baseline (145.127 us; speedup 1.0000x reference)
//
#include <hip/hip_runtime.h>
#include <math.h>

#define T 8192
#define M 4096          // half length (complex FFT size)
#define JS 4104         // padded row stride (elements) for half-spectra
#define B 8
#define CIN 32
#define COUT 32
#define HID 64
#define FT 4

__device__ inline float2 cadd(float2 a, float2 b){ return make_float2(a.x+b.x, a.y+b.y); }
__device__ inline float2 csub(float2 a, float2 b){ return make_float2(a.x-b.x, a.y-b.y); }
__device__ inline float2 cmul(float2 a, float2 b){ return make_float2(a.x*b.x - a.y*b.y, a.x*b.y + a.y*b.x); }
__device__ inline float2 cmulc(float2 a, float2 b){ // a * conj(b)
    return make_float2(a.x*b.x + a.y*b.y, a.y*b.x - a.x*b.y); }
__device__ inline int swzl(int p){ return p ^ ((p >> 5) & 31); }   // in-512 swizzle
__device__ inline int brev12(int v){ return (int)(__brev((unsigned)v) >> 20); }

__device__ inline float gelu_exact(float x){
    return 0.5f*x*(1.0f + erff(x*0.70710678118654752440f));
}

// ---- register-blocked radix-2 groups, 8 pts/thread. tw[k] = e^{-2pi i k/T}, k<4096.
template<int S, int SH0>
__device__ inline void dif_group8(float2 q[8], int r, const float2* __restrict__ tw){
    #pragma unroll
    for (int st = 0; st < 3; ++st){
        const int d = 4 >> st;
        const int sh = SH0 + st;
        #pragma unroll
        for (int k = 0; k < 4; ++k){
            const int jd = k & (d-1);
            const int lo = ((k & ~(d-1)) << 1) | jd;
            const int hi = lo + d;
            float2 w = tw[(r + S*jd) << sh];
            float2 a = q[lo], b = q[hi];
            q[lo] = cadd(a, b);
            q[hi] = cmul(csub(a, b), w);
        }
    }
}
template<int S, int SH0>
__device__ inline void dit_group8(float2 q[8], int r, const float2* __restrict__ tw){
    #pragma unroll
    for (int st = 0; st < 3; ++st){
        const int d = 1 << st;
        const int sh = SH0 - st;
        #pragma unroll
        for (int k = 0; k < 4; ++k){
            const int jd = k & (d-1);
            const int lo = ((k & ~(d-1)) << 1) | jd;
            const int hi = lo + d;
            float2 w = tw[(r + S*jd) << sh];
            float2 a = q[lo];
            float2 t2 = cmulc(q[hi], w);
            q[lo] = cadd(a, t2);
            q[hi] = csub(a, t2);
        }
    }
}

// chunk-pair tables: brev3(c)+brev3(c') = 0 mod 8  ->  {0},{1},{2,3},{4,7},{5,6}
__device__ __constant__ int c0s[4] = {0, 2, 4, 5};
__device__ __constant__ int c1s[4] = {1, 3, 7, 6};

// F1: forward S=512 group. Register-only, no LDS, no barriers.
// sig<256: x rows; sig>=256: H rows. Output W[sig][chunk][tau] (chunk-major).
__global__ __launch_bounds__(256) void fft_pass1(const float* __restrict__ x,
        const float* __restrict__ H, const float2* __restrict__ tw, float2* __restrict__ W){
    const int u = blockIdx.x*256 + threadIdx.x;
    const int sig = u >> 9, tau = u & 511;
    const float* srow = (sig < B*CIN) ? (x + (size_t)sig*T) : (H + (size_t)(sig - B*CIN)*T);
    const float2* zp = (const float2*)srow;            // z[n] = row[2n] + i row[2n+1]
    float2 q[8];
    #pragma unroll
    for (int l = 0; l < 8; ++l) q[l] = zp[tau + 512*l];
    dif_group8<512,1>(q, tau, tw);                     // m = 2048,1024,512
    float2* wp = W + (size_t)sig*M;
    #pragma unroll
    for (int l = 0; l < 8; ++l) wp[l*512 + tau] = q[l];  // pos = tau+512l -> chunk l, offset tau
}

// F2: chunk-local groups (S=64 reg-only; S=8,1 wave-local LDS) + Hermitian split (in-pair).
// block = (pid, sig), 128 thr = 2 waves, wave w owns chunk cc[w]. ONE barrier.
__global__ __launch_bounds__(128) void fft_pass2(const float2* __restrict__ W,
        const float2* __restrict__ tw, float2* __restrict__ Xh, float2* __restrict__ Hh){
    __shared__ float2 ld[1024];
    const int pid = blockIdx.x, sig = blockIdx.y;
    const int tid = threadIdx.x, w = tid >> 6, r = tid & 63;
    const int cc0 = c0s[pid], cc1 = c1s[pid];
    const int c = w ? cc1 : cc0;
    const int base = w << 9;
    const float2* wp = W + (size_t)sig*M + c*512;
    float2 q[8];
    #pragma unroll
    for (int l = 0; l < 8; ++l) q[l] = wp[r + 64*l];   // coalesced
    dif_group8<64,4>(q, r, tw);                        // m = 256,128,64 (register-only)
    #pragma unroll
    for (int l = 0; l < 8; ++l) ld[base + swzl(r + 64*l)] = q[l];
    {   // regroup to stride 8 (wave-local)
        const int b8 = ((r>>3)<<6) | (r&7);
        #pragma unroll
        for (int l = 0; l < 8; ++l) q[l] = ld[base + swzl(b8 + 8*l)];
        dif_group8<8,7>(q, r&7, tw);                   // m = 32,16,8
        #pragma unroll
        for (int l = 0; l < 8; ++l) ld[base + swzl(b8 + 8*l)] = q[l];
    }
    {   // regroup to stride 1 (wave-local)
        const int b1 = r << 3;
        #pragma unroll
        for (int l = 0; l < 8; ++l) q[l] = ld[base + swzl(b1 + l)];
        dif_group8<1,10>(q, 0, tw);                    // m = 4,2,1
        #pragma unroll
        for (int l = 0; l < 8; ++l) ld[base + swzl(b1 + l)] = q[l];
    }
    __syncthreads();                                   // split reads cross-wave (pair)
    float2* dp = (sig < B*CIN) ? (Xh + (size_t)sig*JS) : (Hh + (size_t)(sig - B*CIN)*JS);
    #pragma unroll
    for (int l = 0; l < 8; ++l){
        const int bp = tid + 128*l;                    // coalesced j per l
        const int h  = bp >> 9, p = bp & 511;
        const int j  = ((h ? cc1 : cc0) << 9) + p;
        const int k  = brev12(j);
        const int j2 = brev12((M - k) & (M-1));
        const int p2 = j2 & 511;
        const int h2 = ((j2 >> 9) == cc1) ? 1 : 0;
        float2 Z  = ld[(h  << 9) + swzl(p)];
        float2 Zm = ld[(h2 << 9) + swzl(p2)];
        float2 E = make_float2(0.5f*(Z.x + Zm.x), 0.5f*(Z.y - Zm.y));
        float2 D = make_float2(Z.x - Zm.x, Z.y + Zm.y);        // Z - conj(Zm)
        float2 O = make_float2(0.5f*D.y, -0.5f*D.x);           // -i/2 * D
        dp[j] = cadd(E, cmul(tw[k], O));
        if (j == 0) dp[M] = make_float2(Z.x - Z.y, 0.0f);      // X[M] = ReZ0 - ImZ0
    }
}

// I1: Hermitian combine (in-pair) + chunk-local DIT groups S=1,8 (wave-local), S=64 -> W2.
__global__ __launch_bounds__(128) void ifft_pass1(const float2* __restrict__ Yh,
        const float2* __restrict__ tw, float2* __restrict__ W2){
    __shared__ float2 ld[1024];
    const int pid = blockIdx.x, sig = blockIdx.y;
    const int tid = threadIdx.x, w = tid >> 6, r = tid & 63;
    const int cc0 = c0s[pid], cc1 = c1s[pid];
    const float2* yp = Yh + (size_t)sig*JS;
    #pragma unroll
    for (int l = 0; l < 8; ++l){
        const int bp = tid + 128*l;
        const int h = bp >> 9, p = bp & 511;
        const int j = ((h ? cc1 : cc0) << 9) + p;
        ld[(h << 9) + swzl(p)] = yp[j];                // coalesced per l
    }
    const float2 yM = yp[M];
    __syncthreads();
    // combine, even-j owners (k = brev12(j) < 2048): 4 iterations cover 512 even positions
    #pragma unroll
    for (int l = 0; l < 4; ++l){
        const int bpe = (tid + 128*l) << 1;            // even bp
        const int h = bpe >> 9, p = bpe & 511;
        const int j = ((h ? cc1 : cc0) << 9) + p;
        const int k = brev12(j);                       // < 2048
        float2 Y = ld[(h << 9) + swzl(p)];
        float2 Ym; int h2 = 0, p2 = 0;
        if (k == 0){ Ym = yM; }
        else {
            const int j2 = brev12(M - k);
            p2 = j2 & 511;
            h2 = ((j2 >> 9) == cc1) ? 1 : 0;
            Ym = ld[(h2 << 9) + swzl(p2)];
        }
        float2 E = make_float2(0.5f*(Y.x + Ym.x), 0.5f*(Y.y - Ym.y));
        float2 D = make_float2(0.5f*(Y.x - Ym.x), 0.5f*(Y.y + Ym.y));   // (Y - conj(Ym))/2
        float2 O = cmulc(D, tw[k]);
        ld[(h << 9) + swzl(p)] = make_float2(E.x - O.y, E.y + O.x);     // Z[k]
        if (k != 0)
            ld[(h2 << 9) + swzl(p2)] = make_float2(E.x + O.y, O.x - E.y); // Z[M-k]
    }
    if (pid == 0 && tid == 0){   // j=1 <-> k=2048 self-paired
        float2 Y = ld[swzl(1)];
        float2 E = make_float2(Y.x, 0.0f);
        float2 D = make_float2(0.0f, Y.y);
        float2 O = cmulc(D, tw[2048]);
        ld[swzl(1)] = make_float2(E.x - O.y, E.y + O.x);
    }
    __syncthreads();
    const int base = w << 9;
    float2 q[8];
    {
        const int b1 = r << 3;
        #pragma unroll
        for (int l = 0; l < 8; ++l) q[l] = ld[base + swzl(b1 + l)];
        dit_group8<1,12>(q, 0, tw);                    // m = 1,2,4
        #pragma unroll
        for (int l = 0; l < 8; ++l) ld[base + swzl(b1 + l)] = q[l];
    }
    {
        const int b8 = ((r>>3)<<6) | (r&7);
        #pragma unroll
        for (int l = 0; l < 8; ++l) q[l] = ld[base + swzl(b8 + 8*l)];
        dit_group8<8,9>(q, r&7, tw);                   // m = 8,16,32
        #pragma unroll
        for (int l = 0; l < 8; ++l) ld[base + swzl(b8 + 8*l)] = q[l];
    }
    #pragma unroll
    for (int l = 0; l < 8; ++l) q[l] = ld[base + swzl(r + 64*l)];
    dit_group8<64,6>(q, r, tw);                        // m = 64,128,256
    float2* wp = W2 + (size_t)sig*M + (w ? cc1 : cc0)*512;
    #pragma unroll
    for (int l = 0; l < 8; ++l) wp[r + 64*l] = q[l];   // coalesced
}

// I2: inverse S=512 group, register-only; fused *1/M + bias + real-pack output.
__global__ __launch_bounds__(256) void ifft_pass2(const float2* __restrict__ W2,
        const float2* __restrict__ tw, const float* __restrict__ bias, float* __restrict__ out){
    const int u = blockIdx.x*256 + threadIdx.x;
    const int sig = u >> 9, tau = u & 511;
    const float2* wp = W2 + (size_t)sig*M;
    float2 q[8];
    #pragma unroll
    for (int l = 0; l < 8; ++l) q[l] = wp[tau + 512*l];
    dit_group8<512,3>(q, tau, tw);                     // m = 512,1024,2048
    const float scv = 1.0f/(float)M;
    const float bv = bias[sig & (COUT-1)];
    float2* op = (float2*)(out + (size_t)sig*T);
    #pragma unroll
    for (int l = 0; l < 8; ++l)
        op[tau + 512*l] = make_float2(q[l].x*scv + bv, q[l].y*scv + bv);
}

// MLP hidden state H[h*T + t] + twiddle-table fill fused (blocks 0..15).
#define TB 32
__global__ __launch_bounds__(256) void mlp_hidden(const float* __restrict__ w1, const float* __restrict__ b1,
                           const float* __restrict__ w2, const float* __restrict__ b2,
                           float* __restrict__ H, float2* __restrict__ tw){
    __shared__ float sw1[HID], sb1[HID], sw2[HID*HID], sb2[HID];
    __shared__ float h1s[TB][HID+1];
    const int tid = threadIdx.x;
    if (blockIdx.x < 16){                       // fused tw_init: tw[k]=e^{-2pi i k/T}, k<4096
        const int k = blockIdx.x*256 + tid;
        float ang = -6.28318530717958647692f * (float)k / (float)T;
        float s, c;
        sincosf(ang, &s, &c);
        tw[k] = make_float2(c, s);
    }
    for (int i = tid; i < HID; i += 256){ sw1[i]=w1[i]; sb1[i]=b1[i]; sb2[i]=b2[i]; }
    for (int i = tid; i < HID*HID; i += 256) sw2[i]=w2[i];
    __syncthreads();
    const int t0 = blockIdx.x * TB;
    for (int e = tid; e < TB*HID; e += 256){
        const int tl = e & (TB-1), h = e >> 5;
        const float pos = (float)(t0 + tl) / (float)(T-1);
        h1s[tl][h] = gelu_exact(pos*sw1[h] + sb1[h]);
    }
    __syncthreads();
    const int tl = tid & (TB-1), hg = tid >> 5;   // hg 0..7
    float acc[8];
    #pragma unroll
    for (int u = 0; u < 8; ++u) acc[u] = sb2[hg*8 + u];
    for (int k = 0; k < HID; ++k){
        const float hv = h1s[tl][k];
        const float4 wa = *(const float4*)&sw2[k*HID + hg*8];
        const float4 wb = *(const float4*)&sw2[k*HID + hg*8 + 4];
        acc[0] += hv*wa.x; acc[1] += hv*wa.y; acc[2] += hv*wa.z; acc[3] += hv*wa.w;
        acc[4] += hv*wb.x; acc[5] += hv*wb.y; acc[6] += hv*wb.z; acc[7] += hv*wb.w;
    }
    #pragma unroll
    for (int u = 0; u < 8; ++u)
        H[(size_t)(hg*8 + u)*T + t0 + tl] = gelu_exact(acc[u]);
}

// Fused filter-spectrum GEMM + channel contraction over packed half-spectra.
// grid = (1025, 2): 4 j-columns x o-half. Conflict-engineered SoA LDS.
__global__ __launch_bounds__(256) void filt_contract(const float* __restrict__ w3,
        const float* __restrict__ b3, const float2* __restrict__ Hh,
        const float2* __restrict__ Xh, float2* __restrict__ Yh){
    __shared__ float XsRe[CIN][FT][B+1];    // [i][f][b] pad 9
    __shared__ float XsIm[CIN][FT][B+1];
    __shared__ float FltRe[FT][16][33];     // [f][oL][i] pad 33
    __shared__ float FltIm[FT][16][33];
    const int t = threadIdx.x;
    const int f0 = blockIdx.x * FT;
    const int oh = blockIdx.y;              // o-half: o in [oh*16, oh*16+16)
    {
        const float4* xp4 = (const float4*)(Xh + (size_t)t*JS + f0);
        float4 u0 = xp4[0], u1 = xp4[1];
        const int b = t >> 5, i = t & 31;
        XsRe[i][0][b] = u0.x; XsIm[i][0][b] = u0.y;
        XsRe[i][1][b] = u0.z; XsIm[i][1][b] = u0.w;
        XsRe[i][2][b] = u1.x; XsIm[i][2][b] = u1.y;
        XsRe[i][3][b] = u1.z; XsIm[i][3][b] = u1.w;
    }
    const int oiG = oh*512 + (t << 1);
    float2 acc[2][FT];
    #pragma unroll
    for (int ii = 0; ii < 2; ++ii)
        #pragma unroll
        for (int f = 0; f < FT; ++f) acc[ii][f] = make_float2(0.f, 0.f);
    #pragma unroll 4
    for (int h = 0; h < HID; ++h){
        const float2 w2v = *(const float2*)(w3 + (size_t)h*(CIN*COUT) + oiG);  // coalesced
        const float2* hp = Hh + (size_t)h*JS + f0;                             // block-uniform
        float2 h0 = hp[0], h1 = hp[1], h2 = hp[2], h3 = hp[3];
        const float wv[2] = {w2v.x, w2v.y};
        #pragma unroll
        for (int ii = 0; ii < 2; ++ii){
            acc[ii][0].x += wv[ii]*h0.x; acc[ii][0].y += wv[ii]*h0.y;
            acc[ii][1].x += wv[ii]*h1.x; acc[ii][1].y += wv[ii]*h1.y;
            acc[ii][2].x += wv[ii]*h2.x; acc[ii][2].y += wv[ii]*h2.y;
            acc[ii][3].x += wv[ii]*h3.x; acc[ii][3].y += wv[ii]*h3.y;
        }
    }
    if (f0 == 0){   // DC: filter spectrum += T*b3
        #pragma unroll
        for (int ii = 0; ii < 2; ++ii)
            acc[ii][0].x += (float)T * b3[oiG + ii];
    }
    {
        const int oL = t >> 4;
        const int ib = (t & 15) << 1;
        #pragma unroll
        for (int ii = 0; ii < 2; ++ii)
            #pragma unroll
            for (int f = 0; f < FT; ++f){
                FltRe[f][oL][ib + ii] = acc[ii][f].x;
                FltIm[f][oL][ib + ii] = acc[ii][f].y;
            }
    }
    __syncthreads();
    const int o2 = t >> 4, f2 = (t >> 2) & 3, g = t & 3;
    float2 y[2];
    y[0] = make_float2(0.f, 0.f); y[1] = make_float2(0.f, 0.f);
    #pragma unroll 8
    for (int i0 = 0; i0 < CIN; ++i0){
        const float2 fv = make_float2(FltRe[f2][o2][i0], FltIm[f2][o2][i0]);
        #pragma unroll
        for (int j = 0; j < 2; ++j){
            const int b = (g << 1) | j;
            const float2 xv = make_float2(XsRe[i0][f2][b], XsIm[i0][f2][b]);
            y[j].x += xv.x*fv.x - xv.y*fv.y;
            y[j].y += xv.x*fv.y + xv.y*fv.x;
        }
    }
    if (f0 + f2 <= M){
        #pragma unroll
        for (int j = 0; j < 2; ++j){
            const int b = (g << 1) | j;
            const int o = oh*16 + o2;
            Yh[((size_t)(b*COUT + o))*JS + f0 + f2] = y[j];
        }
    }
}

extern "C" void kernel_launch(void* const* d_in, const int* in_sizes, int n_in,
                              void* d_out, int out_size, void* d_ws, size_t ws_size,
                              hipStream_t stream){
    const float* x    = (const float*)d_in[0];
    const float* w1   = (const float*)d_in[1];
    const float* b1   = (const float*)d_in[2];
    const float* w2   = (const float*)d_in[3];
    const float* b2   = (const float*)d_in[4];
    const float* w3   = (const float*)d_in[5];
    const float* b3   = (const float*)d_in[6];
    const float* bias = (const float*)d_in[7];
    float* out = (float*)d_out;

    // Workspace: Xh@0 (8.4M) | Yh@9M (8.4M) | Hh@18M (2.1M) | H@21M (2M) | tw@23M (32K)
    //            | W@24M (10.5M) | W2@35M (8.4M)   (~44 MB total)
    char* ws = (char*)d_ws;
    float2* Xh = (float2*)ws;
    float2* Yh = (float2*)(ws + (size_t)9*1024*1024);
    float2* Hh = (float2*)(ws + (size_t)18*1024*1024);
    float*  H  = (float*) (ws + (size_t)21*1024*1024);
    float2* tws= (float2*)(ws + (size_t)23*1024*1024);
    float2* W  = (float2*)(ws + (size_t)24*1024*1024);
    float2* W2 = (float2*)(ws + (size_t)35*1024*1024);

    const int NSIG = B*CIN + HID;   // 320
    hipLaunchKernelGGL(mlp_hidden,    dim3(T/TB),        dim3(256), 0, stream, w1, b1, w2, b2, H, tws);
    hipLaunchKernelGGL(fft_pass1,     dim3(NSIG*2),      dim3(256), 0, stream, x, H, tws, W);
    hipLaunchKernelGGL(fft_pass2,     dim3(4, NSIG),     dim3(128), 0, stream, W, tws, Xh, Hh);
    hipLaunchKernelGGL(filt_contract, dim3(M/FT + 1, 2), dim3(256), 0, stream, w3, b3, Hh, Xh, Yh);
    hipLaunchKernelGGL(ifft_pass1,    dim3(4, B*COUT),   dim3(128), 0, stream, Yh, tws, W2);
    hipLaunchKernelGGL(ifft_pass2,    dim3(B*COUT*2),    dim3(256), 0, stream, W2, tws, bias, out);
}